// Round 7
// baseline (1225.032 us; speedup 1.0000x reference)
//
#include <hip/hip_runtime.h>
#include <math.h>

#define T_STEPS 5
#define BATCH 32

// ---- helpers --------------------------------------------------------------
// Row-clamped vectorized 6x8 window load. Clamped rows only ever feed
// DISCARDED outputs (ho >= HOUT), since valid ho <= HIN-5 needs rows <= HIN-1.
template <int WINP, int HIN>
__device__ __forceinline__ void load_win6x8(float (&w)[6][8],
                                            const float* __restrict__ plane,
                                            int row0, int col0) {
#pragma unroll
  for (int rr = 0; rr < 6; ++rr) {
    int r = row0 + rr;
    r = r < HIN - 1 ? r : HIN - 1;
    const float* ip = plane + r * WINP + col0;
    float4 a4 = *reinterpret_cast<const float4*>(ip);
    float4 b4 = *reinterpret_cast<const float4*>(ip + 4);
    w[rr][0] = a4.x; w[rr][1] = a4.y; w[rr][2] = a4.z; w[rr][3] = a4.w;
    w[rr][4] = b4.x; w[rr][5] = b4.y; w[rr][6] = b4.z; w[rr][7] = b4.w;
  }
}

template <int CB>
__device__ __forceinline__ void fma_win(const float (&win)[6][8],
                                        const float* __restrict__ wp,
                                        float (&acc)[4][2][4]) {
#pragma unroll
  for (int kh = 0; kh < 5; ++kh)
#pragma unroll
    for (int kw = 0; kw < 5; ++kw) {
      float4 wv = *reinterpret_cast<const float4*>(wp + (kh * 5 + kw) * CB);
      float wa[4] = {wv.x, wv.y, wv.z, wv.w};
#pragma unroll
      for (int co = 0; co < 4; ++co)
#pragma unroll
        for (int r2 = 0; r2 < 2; ++r2)
#pragma unroll
          for (int c4 = 0; c4 < 4; ++c4)
            acc[co][r2][c4] =
                fmaf(win[kh + r2][kw + c4], wa[co], acc[co][r2][c4]);
    }
}

// ---------------------------------------------------------------------------
// Register-blocked 5x5 VALID conv, fp32, NCHW, padded input rows (WINP).
// tile 32 rows (16 rg x 2) x 16 cols (4 cg x 4) x 16 co (4 cog x 4).
// Weights transposed into LDS once: w[k][co]; per (kh,kw) one wave-uniform
// ds_read_b128 broadcast. Inputs: 12 dwordx4 per ci, REGISTER DOUBLE-BUFFERED
// (prefetch ci+1 while FMA-ing ci; sched_barrier pins issue order).
// Edge tiles: col0 clamped to WINP-8 (clamped threads fully discarded via
// col0r output guard); rows clamped per-row in the loader (see above).
// ---------------------------------------------------------------------------
template <int CIN, int CB, int HIN, int WINP, int HOUT, int WOUT, int TILES_W>
__global__ __launch_bounds__(256, 2) void conv5_rb(
    const float* __restrict__ in, const float* __restrict__ wgt,
    float* __restrict__ out) {
  __shared__ __align__(16) float wlds[CIN * 25 * CB];
  const int tid = threadIdx.x;
  const int n = blockIdx.z;
  const int cob = blockIdx.y;
  const int Cout = gridDim.y * CB;

  for (int i = tid; i < CIN * 25 * CB; i += 256) {
    int co = i & (CB - 1);
    int k = i / CB;
    wlds[i] = wgt[(cob * CB + co) * (CIN * 25) + k];
  }
  __syncthreads();

  const int cog = tid >> 6;        // 0..3 wave-uniform
  const int rg = (tid >> 2) & 15;  // 0..15
  const int cg = tid & 3;          // 0..3
  const int th = blockIdx.x / TILES_W;
  const int twi = blockIdx.x - th * TILES_W;
  const int row0 = th * 32 + rg * 2;
  const int col0r = twi * 16 + cg * 4;                   // output indexing
  const int col0 = col0r < WINP - 8 ? col0r : WINP - 8;  // load (aligned)

  float acc[4][2][4];
#pragma unroll
  for (int a = 0; a < 4; ++a)
#pragma unroll
    for (int b = 0; b < 2; ++b)
#pragma unroll
      for (int c = 0; c < 4; ++c) acc[a][b][c] = 0.f;

  const int HW = HIN * WINP;
  const float* plane = in + (long)n * CIN * HW;

  float A[6][8], Bf[6][8];
  load_win6x8<WINP, HIN>(A, plane, row0, col0);
  for (int ci = 0; ci < CIN; ci += 2) {
    if (ci + 1 < CIN) load_win6x8<WINP, HIN>(Bf, plane + HW, row0, col0);
    __builtin_amdgcn_sched_barrier(0);
    fma_win<CB>(A, &wlds[ci * 25 * CB + cog * 4], acc);
    if (ci + 1 < CIN) {
      if (ci + 2 < CIN)
        load_win6x8<WINP, HIN>(A, plane + 2 * HW, row0, col0);
      __builtin_amdgcn_sched_barrier(0);
      fma_win<CB>(Bf, &wlds[(ci + 1) * 25 * CB + cog * 4], acc);
    }
    plane += 2 * HW;
  }

#pragma unroll
  for (int co = 0; co < 4; ++co) {
    int coG = cob * CB + cog * 4 + co;
    float* op = out + ((long)n * Cout + coG) * (HOUT * WOUT);
#pragma unroll
    for (int r2 = 0; r2 < 2; ++r2) {
      int ho = row0 + r2;
      if (ho < HOUT) {
#pragma unroll
        for (int c4 = 0; c4 < 4; ++c4) {
          int wo = col0r + c4;
          if (wo < WOUT) op[ho * WOUT + wo] = acc[co][r2][c4];
        }
      }
    }
  }
}

// conv4: (160,32,12,12) -> (160,64,8,8). Weights [k][co16] in LDS (51KB),
// input window register double-buffered (25 scalar loads, L1-hot).
__device__ __forceinline__ void load_win25(float (&w)[25],
                                           const float* __restrict__ ip) {
#pragma unroll
  for (int kh = 0; kh < 5; ++kh)
#pragma unroll
    for (int kw = 0; kw < 5; ++kw) w[kh * 5 + kw] = ip[kh * 12 + kw];
}

__device__ __forceinline__ void fma_win25(const float (&win)[25],
                                          const float* __restrict__ wp,
                                          float (&acc)[4]) {
#pragma unroll
  for (int kk = 0; kk < 25; ++kk) {
    float4 wv = *reinterpret_cast<const float4*>(wp + kk * 16);
    acc[0] = fmaf(win[kk], wv.x, acc[0]);
    acc[1] = fmaf(win[kk], wv.y, acc[1]);
    acc[2] = fmaf(win[kk], wv.z, acc[2]);
    acc[3] = fmaf(win[kk], wv.w, acc[3]);
  }
}

__global__ __launch_bounds__(256, 2) void conv4_rb(
    const float* __restrict__ in, const float* __restrict__ wgt,
    float* __restrict__ out) {
  __shared__ __align__(16) float wlds[32 * 25 * 16];  // [k][co16], 51200 B
  const int tid = threadIdx.x;
  const int cob = blockIdx.x;  // 0..3
  const int n = blockIdx.y;    // 0..159
  for (int i = tid; i < 32 * 25 * 16; i += 256) {
    int co = i & 15;
    int k = i >> 4;
    wlds[i] = wgt[(cob * 16 + co) * 800 + k];
  }
  __syncthreads();
  const int px = tid & 63;
  const int cog = tid >> 6;  // wave-uniform
  const int r = px >> 3, c = px & 7;
  float acc[4] = {0.f, 0.f, 0.f, 0.f};
  const float* ip = in + (long)n * 32 * 144 + r * 12 + c;
  float A[25], Bf[25];
  load_win25(A, ip);
  for (int ci = 0; ci < 32; ci += 2) {
    if (ci + 1 < 32) load_win25(Bf, ip + 144);
    __builtin_amdgcn_sched_barrier(0);
    fma_win25(A, &wlds[ci * 25 * 16 + cog * 4], acc);
    if (ci + 1 < 32) {
      if (ci + 2 < 32) load_win25(A, ip + 288);
      __builtin_amdgcn_sched_barrier(0);
      fma_win25(Bf, &wlds[(ci + 1) * 25 * 16 + cog * 4], acc);
    }
    ip += 288;
  }
  float* op = out + ((long)n * 64 + cob * 16 + cog * 4) * 64 + px;
#pragma unroll
  for (int j = 0; j < 4; ++j) op[j * 64] = acc[j];
}

// BN stats: two-stage deterministic partial sums in double ------------------
__global__ __launch_bounds__(256) void bn_partial(
    const float* __restrict__ y, int C, int M, int HW, double inv_hw,
    double* __restrict__ psum, double* __restrict__ psq, int S) {
  const int c = blockIdx.x / S;
  const int s = blockIdx.x - c * S;
  const int tid = threadIdx.x;
  double sum = 0.0, sumsq = 0.0;
  for (int i = s * 256 + tid; i < M; i += S * 256) {
    int n = (int)((double)i * inv_hw);
    int hw = i - n * HW;
    if (hw < 0) { n--; hw += HW; }
    else if (hw >= HW) { n++; hw -= HW; }
    float v = y[((long)n * C + c) * (long)HW + hw];
    sum += (double)v;
    sumsq += (double)v * (double)v;
  }
  __shared__ double ls[256], ls2[256];
  ls[tid] = sum;
  ls2[tid] = sumsq;
  __syncthreads();
  for (int off = 128; off > 0; off >>= 1) {
    if (tid < off) {
      ls[tid] += ls[tid + off];
      ls2[tid] += ls2[tid + off];
    }
    __syncthreads();
  }
  if (tid == 0) {
    psum[blockIdx.x] = ls[0];
    psq[blockIdx.x] = ls2[0];
  }
}

__global__ void bn_finalize(const double* __restrict__ psum,
                            const double* __restrict__ psq,
                            const float* __restrict__ gamma,
                            const float* __restrict__ beta,
                            float* __restrict__ scale,
                            float* __restrict__ shift, int C, int S,
                            double invM) {
  int c = threadIdx.x;
  if (c >= C) return;
  double s = 0.0, s2 = 0.0;
  for (int i = 0; i < S; ++i) {
    s += psum[c * S + i];
    s2 += psq[c * S + i];
  }
  double m = s * invM;
  double var = s2 * invM - m * m;
  double r = 1.0 / sqrt(var + 1e-5);
  double sc = (double)gamma[c] * r;
  scale[c] = (float)sc;
  shift[c] = (float)((double)beta[c] - m * sc);
}

// Fused BN-affine + 5-step PLIF + 2x2 maxpool. Writes pool output with
// padded row width PWp (pad cols zeroed) so the next conv can float4-load.
__global__ __launch_bounds__(256) void plif_pool(
    const float* __restrict__ y, const float* __restrict__ scale,
    const float* __restrict__ shift, const float* __restrict__ wlif,
    float* __restrict__ p, int C, int H, int W, int PH, int PW, int PWp,
    long t_stride) {
  int idx = blockIdx.x * 256 + threadIdx.x;
  int total = BATCH * C * PH * PWp;
  if (idx >= total) return;
  int pw = idx % PWp;
  int t2 = idx / PWp;
  int ph = t2 % PH;
  t2 /= PH;
  int c = t2 % C;
  int b = t2 / C;
  const long pstr = (long)BATCH * C * PH * PWp;
  const long pbase = (((long)b * C + c) * PH + ph) * PWp + pw;
  if (pw >= PW) {
#pragma unroll
    for (int t = 0; t < T_STEPS; ++t) p[t * pstr + pbase] = 0.f;
    return;
  }
  const float sc = scale[c], sh = shift[c];
  const float decay = 1.f / (1.f + expf(-wlif[0]));
  const long base = (((long)b * C + c) * H + 2 * ph) * W + 2 * pw;
  float v0 = 0.f, v1 = 0.f, v2 = 0.f, v3 = 0.f;
#pragma unroll
  for (int t = 0; t < T_STEPS; ++t) {
    const float* yp = y + t * t_stride + base;
    float x0 = yp[0] * sc + sh;
    float x1 = yp[1] * sc + sh;
    float x2 = yp[W] * sc + sh;
    float x3 = yp[W + 1] * sc + sh;
    v0 += (x0 - v0) * decay;
    v1 += (x1 - v1) * decay;
    v2 += (x2 - v2) * decay;
    v3 += (x3 - v3) * decay;
    float s0 = (v0 >= 1.f) ? 1.f : 0.f;
    float s1 = (v1 >= 1.f) ? 1.f : 0.f;
    float s2 = (v2 >= 1.f) ? 1.f : 0.f;
    float s3 = (v3 >= 1.f) ? 1.f : 0.f;
    v0 = (v0 >= 1.f) ? 0.f : v0;
    v1 = (v1 >= 1.f) ? 0.f : v1;
    v2 = (v2 >= 1.f) ? 0.f : v2;
    v3 = (v3 >= 1.f) ? 0.f : v3;
    p[t * pstr + pbase] = fmaxf(fmaxf(s0, s1), fmaxf(s2, s3));
  }
}

// fc1: n-tiled GEMM. Block = 256 o-columns x 8 batch rows (x staged in LDS,
// broadcast reads). Weight row read ONCE per 8 n (was once per n).
__global__ __launch_bounds__(256, 2) void fc1_tiled(
    const float* __restrict__ x, const float* __restrict__ w,
    float* __restrict__ out) {
  __shared__ __align__(16) float xs[8][1024];  // 32 KB
  const int tid = threadIdx.x;
  const int n0 = blockIdx.y * 8;
  const int o = blockIdx.x * 256 + tid;
  for (int i = tid; i < 8 * 1024; i += 256) {
    int nn = i >> 10, k = i & 1023;
    xs[nn][k] = x[(long)(n0 + nn) * 1024 + k];
  }
  __syncthreads();
  const float4* wr = reinterpret_cast<const float4*>(w + (long)o * 1024);
  float acc[8] = {0.f, 0.f, 0.f, 0.f, 0.f, 0.f, 0.f, 0.f};
  for (int k4 = 0; k4 < 256; ++k4) {
    float4 w4 = wr[k4];
#pragma unroll
    for (int nn = 0; nn < 8; ++nn) {
      float4 xv = *reinterpret_cast<const float4*>(&xs[nn][k4 * 4]);
      acc[nn] += w4.x * xv.x + w4.y * xv.y + w4.z * xv.z + w4.w * xv.w;
    }
  }
#pragma unroll
  for (int nn = 0; nn < 8; ++nn) out[(long)(n0 + nn) * 1024 + o] = acc[nn];
}

// FC (used for fc2): out[n,o] = dot(x[n,:], w[o,:]) -----------------------
__global__ __launch_bounds__(256) void fc_kernel(const float* __restrict__ x,
                                                 const float* __restrict__ w,
                                                 float* __restrict__ out,
                                                 int K, int O, int obpn) {
  int n = blockIdx.x / obpn;
  int o = (blockIdx.x - n * obpn) * 256 + threadIdx.x;
  if (o >= O) return;
  const float4* xr = reinterpret_cast<const float4*>(x + (long)n * K);
  const float4* wr = reinterpret_cast<const float4*>(w + (long)o * K);
  float acc = 0.f;
  for (int k = 0; k < K / 4; ++k) {
    float4 a = xr[k];
    float4 b = wr[k];
    acc += a.x * b.x + a.y * b.y + a.z * b.z + a.w * b.w;
  }
  out[(long)n * O + o] = acc;
}

// PLIF over time for FC activations (adds bias), writes spike seq -----------
__global__ __launch_bounds__(256) void plif_fc(const float* __restrict__ h,
                                               const float* __restrict__ bias,
                                               const float* __restrict__ wlif,
                                               float* __restrict__ s_out,
                                               int F) {
  int idx = blockIdx.x * 256 + threadIdx.x;
  if (idx >= BATCH * F) return;
  int f = idx % F;
  int b = idx / F;
  const float decay = 1.f / (1.f + expf(-wlif[0]));
  const float bi = bias[f];
  float v = 0.f;
#pragma unroll
  for (int t = 0; t < T_STEPS; ++t) {
    long off = ((long)(t * BATCH + b)) * F + f;
    float x = h[off] + bi;
    v += (x - v) * decay;
    float s = (v >= 1.f) ? 1.f : 0.f;
    v = (v >= 1.f) ? 0.f : v;
    s_out[off] = s;
  }
}

// Final PLIF + mean over T --------------------------------------------------
__global__ __launch_bounds__(256) void plif_mean(const float* __restrict__ h,
                                                 const float* __restrict__ bias,
                                                 const float* __restrict__ wlif,
                                                 float* __restrict__ out,
                                                 int O) {
  int idx = blockIdx.x * 256 + threadIdx.x;
  if (idx >= BATCH * O) return;
  int o = idx % O;
  int b = idx / O;
  const float decay = 1.f / (1.f + expf(-wlif[0]));
  const float bi = bias[o];
  float v = 0.f, sum = 0.f;
#pragma unroll
  for (int t = 0; t < T_STEPS; ++t) {
    float x = h[(long)(t * BATCH + b) * O + o] + bi;
    v += (x - v) * decay;
    float s = (v >= 1.f) ? 1.f : 0.f;
    v = (v >= 1.f) ? 0.f : v;
    sum += s;
  }
  out[(long)b * O + o] = sum / 5.0f;
}

// ---------------------------------------------------------------------------
extern "C" void kernel_launch(void* const* d_in, const int* in_sizes, int n_in,
                              void* d_out, int out_size, void* d_ws,
                              size_t ws_size, hipStream_t stream) {
  const float* x = (const float*)d_in[0];
  const float* wc1 = (const float*)d_in[1];
  const float* wc2 = (const float*)d_in[2];
  const float* wc3 = (const float*)d_in[3];
  const float* wc4 = (const float*)d_in[4];
  const float* g1 = (const float*)d_in[5];
  const float* b1 = (const float*)d_in[6];
  const float* g2 = (const float*)d_in[7];
  const float* b2 = (const float*)d_in[8];
  const float* g3 = (const float*)d_in[9];
  const float* b3 = (const float*)d_in[10];
  const float* g4 = (const float*)d_in[11];
  const float* b4 = (const float*)d_in[12];
  const float* wl1 = (const float*)d_in[13];
  const float* wl2 = (const float*)d_in[14];
  const float* wl3 = (const float*)d_in[15];
  const float* wl4 = (const float*)d_in[16];
  const float* wl5 = (const float*)d_in[17];
  const float* wl6 = (const float*)d_in[18];
  const float* fc1w = (const float*)d_in[19];
  const float* fc1b = (const float*)d_in[20];
  const float* fc2w = (const float*)d_in[21];
  const float* fc2b = (const float*)d_in[22];
  float* out = (float*)d_out;

  // Workspace: Y 68,894,720 B | P 40,632,320 B (padded pool) | stats
  char* ws = (char*)d_ws;
  float* Y = (float*)ws;
  float* P = (float*)(ws + 68894720);
  char* Sb = ws + 68894720 + 40632320;
  double* psum = (double*)Sb;
  double* psq = psum + 64 * 32;
  float* scale = (float*)(psq + 64 * 32);
  float* shift = scale + 64;

  const int S = 32;

  // ---- block 1: conv1 on B=32 only (input replicated over T) ----
  conv5_rb<3, 16, 128, 128, 124, 124, 8>
      <<<dim3(4 * 8, 1, 32), 256, 0, stream>>>(x, wc1, Y);
  {
    int HW = 124 * 124, M = 32 * HW;
    bn_partial<<<16 * S, 256, 0, stream>>>(Y, 16, M, HW, 1.0 / HW, psum, psq, S);
    bn_finalize<<<1, 64, 0, stream>>>(psum, psq, g1, b1, scale, shift, 16, S,
                                      1.0 / (double)M);
  }
  {  // pool1 out: (5,32,16,62,PWp=64)
    int total = BATCH * 16 * 62 * 64;
    plif_pool<<<(total + 255) / 256, 256, 0, stream>>>(
        Y, scale, shift, wl1, P, 16, 124, 124, 62, 62, 64, 0L);
  }

  // ---- block 2: conv2 (160,16,62x64p) -> (160,32,58,58) ----
  conv5_rb<16, 16, 62, 64, 58, 58, 4>
      <<<dim3(2 * 4, 2, 160), 256, 0, stream>>>(P, wc2, Y);
  {
    int HW = 58 * 58, M = 160 * HW;
    bn_partial<<<32 * S, 256, 0, stream>>>(Y, 32, M, HW, 1.0 / HW, psum, psq, S);
    bn_finalize<<<1, 64, 0, stream>>>(psum, psq, g2, b2, scale, shift, 32, S,
                                      1.0 / (double)M);
  }
  {  // pool2 out: (5,32,32,29,PWp=32)
    int total = BATCH * 32 * 29 * 32;
    plif_pool<<<(total + 255) / 256, 256, 0, stream>>>(
        Y, scale, shift, wl2, P, 32, 58, 58, 29, 29, 32,
        (long)BATCH * 32 * 58 * 58);
  }

  // ---- block 3: conv3 (160,32,29x32p) -> (160,32,25,25) ----
  conv5_rb<32, 16, 29, 32, 25, 25, 2>
      <<<dim3(1 * 2, 2, 160), 256, 0, stream>>>(P, wc3, Y);
  {
    int HW = 25 * 25, M = 160 * HW;
    bn_partial<<<32 * S, 256, 0, stream>>>(Y, 32, M, HW, 1.0 / HW, psum, psq, S);
    bn_finalize<<<1, 64, 0, stream>>>(psum, psq, g3, b3, scale, shift, 32, S,
                                      1.0 / (double)M);
  }
  {  // pool3 out: (5,32,32,12,12)
    int total = BATCH * 32 * 12 * 12;
    plif_pool<<<(total + 255) / 256, 256, 0, stream>>>(
        Y, scale, shift, wl3, P, 32, 25, 25, 12, 12, 12,
        (long)BATCH * 32 * 25 * 25);
  }

  // ---- block 4: conv4 (160,32,12,12) -> (160,64,8,8) ----
  conv4_rb<<<dim3(4, 160), 256, 0, stream>>>(P, wc4, Y);
  {
    int HW = 8 * 8, M = 160 * HW;
    bn_partial<<<64 * S, 256, 0, stream>>>(Y, 64, M, HW, 1.0 / HW, psum, psq, S);
    bn_finalize<<<1, 64, 0, stream>>>(psum, psq, g4, b4, scale, shift, 64, S,
                                      1.0 / (double)M);
  }
  {  // pool4 out: (5,32,64,4,4)
    int total = BATCH * 64 * 4 * 4;
    plif_pool<<<(total + 255) / 256, 256, 0, stream>>>(
        Y, scale, shift, wl4, P, 64, 8, 8, 4, 4, 4, (long)BATCH * 64 * 8 * 8);
  }

  // ---- FC head ----
  float* h1 = Y;
  float* s1 = P;
  float* h2 = Y + 163840;
  fc1_tiled<<<dim3(4, 20), 256, 0, stream>>>(P, fc1w, h1);
  plif_fc<<<(BATCH * 1024 + 255) / 256, 256, 0, stream>>>(h1, fc1b, wl5, s1,
                                                          1024);
  fc_kernel<<<160 * 1, 256, 0, stream>>>(s1, fc2w, h2, 1024, 10, 1);
  plif_mean<<<(BATCH * 10 + 255) / 256, 256, 0, stream>>>(h2, fc2b, wl6, out,
                                                          10);
}

// Round 8
// 784.490 us; speedup vs baseline: 1.5616x; 1.5616x over previous
//
#include <hip/hip_runtime.h>
#include <math.h>

#define T_STEPS 5
#define BATCH 32

// async global->LDS: 16B per lane, dest = wave-uniform base + lane*16
__device__ __forceinline__ void stage16(const float* g, float* l) {
  __builtin_amdgcn_global_load_lds(
      (const __attribute__((address_space(1))) void*)g,
      (__attribute__((address_space(3))) void*)l, 16, 0, 0);
}

template <int CB>
__device__ __forceinline__ void fma_win(const float (&win)[6][8],
                                        const float* __restrict__ wp,
                                        float (&acc)[4][2][4]) {
#pragma unroll
  for (int kh = 0; kh < 5; ++kh)
#pragma unroll
    for (int kw = 0; kw < 5; ++kw) {
      float4 wv = *reinterpret_cast<const float4*>(wp + (kh * 5 + kw) * CB);
      float wa[4] = {wv.x, wv.y, wv.z, wv.w};
#pragma unroll
      for (int co = 0; co < 4; ++co)
#pragma unroll
        for (int r2 = 0; r2 < 2; ++r2)
#pragma unroll
          for (int c4 = 0; c4 < 4; ++c4)
            acc[co][r2][c4] =
                fmaf(win[kh + r2][kw + c4], wa[co], acc[co][r2][c4]);
    }
}

// ---------------------------------------------------------------------------
// LDS-staged 5x5 VALID conv, fp32, NCHW, padded input rows (WINP).
// Block tile: 32 rows x 16 cols x CB=16 co. tid = cog*64 + rg*4 + cg.
// Input patch per ci: 36 rows x 28 floats, staged by global_load_lds DMA
// (7 lanes/row x 16B -> LDS layout is linear in tid: off = 4*tid).
// Double-buffered in LDS; prefetch ci+1 with vmcnt(1) (never 0 mid-loop);
// raw s_barrier pair + lgkmcnt(0) + sched_barrier pins (T3-lite).
// Row-clamped source (clamped rows feed only discarded outputs); CLAMPF adds
// flat clamp vs SRCMAX for real-input conv1 (col-wrap reads stay in-bounds).
// Weights [k][co] in LDS; per (kh,kw) one wave-uniform b128 broadcast.
// ---------------------------------------------------------------------------
template <int CIN, int CB, int HIN, int WINP, int HOUT, int WOUT, int TILES_W,
          bool CLAMPF, long SRCMAX>
__global__ __launch_bounds__(256, 3) void conv5_lds(
    const float* __restrict__ in, const float* __restrict__ wgt,
    float* __restrict__ out) {
  __shared__ __align__(16) float wlds[CIN * 25 * CB];
  __shared__ __align__(16) float patch[2][1024];
  const int tid = threadIdx.x;
  const int n = blockIdx.z;
  const int cob = blockIdx.y;
  const int Cout = gridDim.y * CB;
  const int HW = HIN * WINP;

  const int th = blockIdx.x / TILES_W;
  const int twi = blockIdx.x - th * TILES_W;
  const int rowblk0 = th * 32;
  const int colblk0 = twi * 16;

  // per-lane DMA source offset (floats), constant across ci
  const int r_s = tid / 7;
  const int c_s = tid - r_s * 7;
  int gr = rowblk0 + r_s;
  gr = gr < HIN - 1 ? gr : HIN - 1;  // clamped rows feed discarded outputs only
  const long src0 = (long)n * CIN * HW + (long)gr * WINP + colblk0 + c_s * 4;
  const int wv = tid >> 6;  // wave id (wave-uniform)
  float* ldsdst0 = &patch[0][wv * 256];
  float* ldsdst1 = &patch[1][wv * 256];

  // issue stage(ci=0) immediately, hide behind weight staging
  {
    long o = src0;
    if (CLAMPF) o = o < SRCMAX ? o : SRCMAX;
    stage16(in + o, ldsdst0);
  }
  for (int i = tid; i < CIN * 25 * CB; i += 256) {
    int co = i & (CB - 1);
    int k = i / CB;
    wlds[i] = wgt[(cob * CB + co) * (CIN * 25) + k];
  }
  __syncthreads();  // drains stage(0) DMA + weight stores

  const int cog = tid >> 6;
  const int rg2 = ((tid >> 2) & 15) * 2;
  const int cg4 = (tid & 3) * 4;

  float acc[4][2][4];
#pragma unroll
  for (int a = 0; a < 4; ++a)
#pragma unroll
    for (int b = 0; b < 2; ++b)
#pragma unroll
      for (int c = 0; c < 4; ++c) acc[a][b][c] = 0.f;

  for (int ci = 0; ci < CIN; ++ci) {
    if (ci + 1 < CIN) {  // prefetch next ci into other buffer
      long o = src0 + (long)(ci + 1) * HW;
      if (CLAMPF) o = o < SRCMAX ? o : SRCMAX;
      stage16(in + o, ((ci + 1) & 1) ? ldsdst1 : ldsdst0);
      asm volatile("s_waitcnt vmcnt(1)" ::: "memory");  // stage(ci) done
    } else {
      asm volatile("s_waitcnt vmcnt(0)" ::: "memory");
    }
    __builtin_amdgcn_sched_barrier(0);
    __builtin_amdgcn_s_barrier();  // all waves: patch[ci&1] fully staged
    __builtin_amdgcn_sched_barrier(0);

    float win[6][8];
    const float* pb = &patch[ci & 1][0];
#pragma unroll
    for (int rr = 0; rr < 6; ++rr) {
      float4 a4 = *reinterpret_cast<const float4*>(pb + (rg2 + rr) * 28 + cg4);
      float4 b4 =
          *reinterpret_cast<const float4*>(pb + (rg2 + rr) * 28 + cg4 + 4);
      win[rr][0] = a4.x; win[rr][1] = a4.y; win[rr][2] = a4.z;
      win[rr][3] = a4.w; win[rr][4] = b4.x; win[rr][5] = b4.y;
      win[rr][6] = b4.z; win[rr][7] = b4.w;
    }
    asm volatile("s_waitcnt lgkmcnt(0)" ::: "memory");  // reads complete
    __builtin_amdgcn_sched_barrier(0);
    __builtin_amdgcn_s_barrier();  // safe for next DMA to overwrite
    __builtin_amdgcn_sched_barrier(0);

    fma_win<CB>(win, &wlds[ci * 25 * CB + cog * 4], acc);
  }

#pragma unroll
  for (int co = 0; co < 4; ++co) {
    int coG = cob * CB + cog * 4 + co;
    float* op = out + ((long)n * Cout + coG) * (HOUT * WOUT);
#pragma unroll
    for (int r2 = 0; r2 < 2; ++r2) {
      int ho = rowblk0 + rg2 + r2;
      if (ho < HOUT) {
#pragma unroll
        for (int c4 = 0; c4 < 4; ++c4) {
          int wo = colblk0 + cg4 + c4;
          if (wo < WOUT) op[ho * WOUT + wo] = acc[co][r2][c4];
        }
      }
    }
  }
}

// conv4: (160,32,12,12) -> (160,64,8,8). Weights [k][co16] in LDS,
// single-buffer window (L2-hot input), simple schedule.
__global__ __launch_bounds__(256) void conv4_rb(const float* __restrict__ in,
                                                const float* __restrict__ wgt,
                                                float* __restrict__ out) {
  __shared__ __align__(16) float wlds[32 * 25 * 16];
  const int tid = threadIdx.x;
  const int cob = blockIdx.x;  // 0..3
  const int n = blockIdx.y;    // 0..159
  for (int i = tid; i < 32 * 25 * 16; i += 256) {
    int co = i & 15;
    int k = i >> 4;
    wlds[i] = wgt[(cob * 16 + co) * 800 + k];
  }
  __syncthreads();
  const int px = tid & 63;
  const int cog = tid >> 6;
  const int r = px >> 3, c = px & 7;
  float acc[4] = {0.f, 0.f, 0.f, 0.f};
  const float* ip = in + (long)n * 32 * 144 + r * 12 + c;
  for (int ci = 0; ci < 32; ++ci) {
    float win[25];
#pragma unroll
    for (int kh = 0; kh < 5; ++kh)
#pragma unroll
      for (int kw = 0; kw < 5; ++kw) win[kh * 5 + kw] = ip[kh * 12 + kw];
    ip += 144;
    const float* wp = &wlds[ci * 400 + cog * 4];
#pragma unroll
    for (int kk = 0; kk < 25; ++kk) {
      float4 wv = *reinterpret_cast<const float4*>(wp + kk * 16);
      acc[0] = fmaf(win[kk], wv.x, acc[0]);
      acc[1] = fmaf(win[kk], wv.y, acc[1]);
      acc[2] = fmaf(win[kk], wv.z, acc[2]);
      acc[3] = fmaf(win[kk], wv.w, acc[3]);
    }
  }
  float* op = out + ((long)n * 64 + cob * 16 + cog * 4) * 64 + px;
#pragma unroll
  for (int j = 0; j < 4; ++j) op[j * 64] = acc[j];
}

// BN stats: two-stage deterministic partial sums in double ------------------
__global__ __launch_bounds__(256) void bn_partial(
    const float* __restrict__ y, int C, int M, int HW, double inv_hw,
    double* __restrict__ psum, double* __restrict__ psq, int S) {
  const int c = blockIdx.x / S;
  const int s = blockIdx.x - c * S;
  const int tid = threadIdx.x;
  double sum = 0.0, sumsq = 0.0;
  for (int i = s * 256 + tid; i < M; i += S * 256) {
    int n = (int)((double)i * inv_hw);
    int hw = i - n * HW;
    if (hw < 0) { n--; hw += HW; }
    else if (hw >= HW) { n++; hw -= HW; }
    float v = y[((long)n * C + c) * (long)HW + hw];
    sum += (double)v;
    sumsq += (double)v * (double)v;
  }
  __shared__ double ls[256], ls2[256];
  ls[tid] = sum;
  ls2[tid] = sumsq;
  __syncthreads();
  for (int off = 128; off > 0; off >>= 1) {
    if (tid < off) {
      ls[tid] += ls[tid + off];
      ls2[tid] += ls2[tid + off];
    }
    __syncthreads();
  }
  if (tid == 0) {
    psum[blockIdx.x] = ls[0];
    psq[blockIdx.x] = ls2[0];
  }
}

__global__ void bn_finalize(const double* __restrict__ psum,
                            const double* __restrict__ psq,
                            const float* __restrict__ gamma,
                            const float* __restrict__ beta,
                            float* __restrict__ scale,
                            float* __restrict__ shift, int C, int S,
                            double invM) {
  int c = threadIdx.x;
  if (c >= C) return;
  double s = 0.0, s2 = 0.0;
  for (int i = 0; i < S; ++i) {
    s += psum[c * S + i];
    s2 += psq[c * S + i];
  }
  double m = s * invM;
  double var = s2 * invM - m * m;
  double r = 1.0 / sqrt(var + 1e-5);
  double sc = (double)gamma[c] * r;
  scale[c] = (float)sc;
  shift[c] = (float)((double)beta[c] - m * sc);
}

// Fused BN-affine + 5-step PLIF + 2x2 maxpool; padded pool rows (PWp). ------
__global__ __launch_bounds__(256) void plif_pool(
    const float* __restrict__ y, const float* __restrict__ scale,
    const float* __restrict__ shift, const float* __restrict__ wlif,
    float* __restrict__ p, int C, int H, int W, int PH, int PW, int PWp,
    long t_stride) {
  int idx = blockIdx.x * 256 + threadIdx.x;
  int total = BATCH * C * PH * PWp;
  if (idx >= total) return;
  int pw = idx % PWp;
  int t2 = idx / PWp;
  int ph = t2 % PH;
  t2 /= PH;
  int c = t2 % C;
  int b = t2 / C;
  const long pstr = (long)BATCH * C * PH * PWp;
  const long pbase = (((long)b * C + c) * PH + ph) * PWp + pw;
  if (pw >= PW) {
#pragma unroll
    for (int t = 0; t < T_STEPS; ++t) p[t * pstr + pbase] = 0.f;
    return;
  }
  const float sc = scale[c], sh = shift[c];
  const float decay = 1.f / (1.f + expf(-wlif[0]));
  const long base = (((long)b * C + c) * H + 2 * ph) * W + 2 * pw;
  float v0 = 0.f, v1 = 0.f, v2 = 0.f, v3 = 0.f;
#pragma unroll
  for (int t = 0; t < T_STEPS; ++t) {
    const float* yp = y + t * t_stride + base;
    float x0 = yp[0] * sc + sh;
    float x1 = yp[1] * sc + sh;
    float x2 = yp[W] * sc + sh;
    float x3 = yp[W + 1] * sc + sh;
    v0 += (x0 - v0) * decay;
    v1 += (x1 - v1) * decay;
    v2 += (x2 - v2) * decay;
    v3 += (x3 - v3) * decay;
    float s0 = (v0 >= 1.f) ? 1.f : 0.f;
    float s1 = (v1 >= 1.f) ? 1.f : 0.f;
    float s2 = (v2 >= 1.f) ? 1.f : 0.f;
    float s3 = (v3 >= 1.f) ? 1.f : 0.f;
    v0 = (v0 >= 1.f) ? 0.f : v0;
    v1 = (v1 >= 1.f) ? 0.f : v1;
    v2 = (v2 >= 1.f) ? 0.f : v2;
    v3 = (v3 >= 1.f) ? 0.f : v3;
    p[t * pstr + pbase] = fmaxf(fmaxf(s0, s1), fmaxf(s2, s3));
  }
}

// fc1: n-tiled GEMM, 8 batch rows staged in LDS -----------------------------
__global__ __launch_bounds__(256, 2) void fc1_tiled(
    const float* __restrict__ x, const float* __restrict__ w,
    float* __restrict__ out) {
  __shared__ __align__(16) float xs[8][1024];
  const int tid = threadIdx.x;
  const int n0 = blockIdx.y * 8;
  const int o = blockIdx.x * 256 + tid;
  for (int i = tid; i < 8 * 1024; i += 256) {
    int nn = i >> 10, k = i & 1023;
    xs[nn][k] = x[(long)(n0 + nn) * 1024 + k];
  }
  __syncthreads();
  const float4* wr = reinterpret_cast<const float4*>(w + (long)o * 1024);
  float acc[8] = {0.f, 0.f, 0.f, 0.f, 0.f, 0.f, 0.f, 0.f};
  for (int k4 = 0; k4 < 256; ++k4) {
    float4 w4 = wr[k4];
#pragma unroll
    for (int nn = 0; nn < 8; ++nn) {
      float4 xv = *reinterpret_cast<const float4*>(&xs[nn][k4 * 4]);
      acc[nn] += w4.x * xv.x + w4.y * xv.y + w4.z * xv.z + w4.w * xv.w;
    }
  }
#pragma unroll
  for (int nn = 0; nn < 8; ++nn) out[(long)(n0 + nn) * 1024 + o] = acc[nn];
}

// fc2 ----------------------------------------------------------------------
__global__ __launch_bounds__(256) void fc_kernel(const float* __restrict__ x,
                                                 const float* __restrict__ w,
                                                 float* __restrict__ out,
                                                 int K, int O, int obpn) {
  int n = blockIdx.x / obpn;
  int o = (blockIdx.x - n * obpn) * 256 + threadIdx.x;
  if (o >= O) return;
  const float4* xr = reinterpret_cast<const float4*>(x + (long)n * K);
  const float4* wr = reinterpret_cast<const float4*>(w + (long)o * K);
  float acc = 0.f;
  for (int k = 0; k < K / 4; ++k) {
    float4 a = xr[k];
    float4 b = wr[k];
    acc += a.x * b.x + a.y * b.y + a.z * b.z + a.w * b.w;
  }
  out[(long)n * O + o] = acc;
}

__global__ __launch_bounds__(256) void plif_fc(const float* __restrict__ h,
                                               const float* __restrict__ bias,
                                               const float* __restrict__ wlif,
                                               float* __restrict__ s_out,
                                               int F) {
  int idx = blockIdx.x * 256 + threadIdx.x;
  if (idx >= BATCH * F) return;
  int f = idx % F;
  int b = idx / F;
  const float decay = 1.f / (1.f + expf(-wlif[0]));
  const float bi = bias[f];
  float v = 0.f;
#pragma unroll
  for (int t = 0; t < T_STEPS; ++t) {
    long off = ((long)(t * BATCH + b)) * F + f;
    float x = h[off] + bi;
    v += (x - v) * decay;
    float s = (v >= 1.f) ? 1.f : 0.f;
    v = (v >= 1.f) ? 0.f : v;
    s_out[off] = s;
  }
}

__global__ __launch_bounds__(256) void plif_mean(const float* __restrict__ h,
                                                 const float* __restrict__ bias,
                                                 const float* __restrict__ wlif,
                                                 float* __restrict__ out,
                                                 int O) {
  int idx = blockIdx.x * 256 + threadIdx.x;
  if (idx >= BATCH * O) return;
  int o = idx % O;
  int b = idx / O;
  const float decay = 1.f / (1.f + expf(-wlif[0]));
  const float bi = bias[o];
  float v = 0.f, sum = 0.f;
#pragma unroll
  for (int t = 0; t < T_STEPS; ++t) {
    float x = h[(long)(t * BATCH + b) * O + o] + bi;
    v += (x - v) * decay;
    float s = (v >= 1.f) ? 1.f : 0.f;
    v = (v >= 1.f) ? 0.f : v;
    sum += s;
  }
  out[(long)b * O + o] = sum / 5.0f;
}

// ---------------------------------------------------------------------------
extern "C" void kernel_launch(void* const* d_in, const int* in_sizes, int n_in,
                              void* d_out, int out_size, void* d_ws,
                              size_t ws_size, hipStream_t stream) {
  const float* x = (const float*)d_in[0];
  const float* wc1 = (const float*)d_in[1];
  const float* wc2 = (const float*)d_in[2];
  const float* wc3 = (const float*)d_in[3];
  const float* wc4 = (const float*)d_in[4];
  const float* g1 = (const float*)d_in[5];
  const float* b1 = (const float*)d_in[6];
  const float* g2 = (const float*)d_in[7];
  const float* b2 = (const float*)d_in[8];
  const float* g3 = (const float*)d_in[9];
  const float* b3 = (const float*)d_in[10];
  const float* g4 = (const float*)d_in[11];
  const float* b4 = (const float*)d_in[12];
  const float* wl1 = (const float*)d_in[13];
  const float* wl2 = (const float*)d_in[14];
  const float* wl3 = (const float*)d_in[15];
  const float* wl4 = (const float*)d_in[16];
  const float* wl5 = (const float*)d_in[17];
  const float* wl6 = (const float*)d_in[18];
  const float* fc1w = (const float*)d_in[19];
  const float* fc1b = (const float*)d_in[20];
  const float* fc2w = (const float*)d_in[21];
  const float* fc2b = (const float*)d_in[22];
  float* out = (float*)d_out;

  // Workspace: Y 68,894,720 B | P 40,632,320 B (padded pool) | stats
  char* ws = (char*)d_ws;
  float* Y = (float*)ws;
  float* P = (float*)(ws + 68894720);
  char* Sb = ws + 68894720 + 40632320;
  double* psum = (double*)Sb;
  double* psq = psum + 64 * 32;
  float* scale = (float*)(psq + 64 * 32);
  float* shift = scale + 64;

  const int S = 32;

  // ---- block 1: conv1 on B=32 only (input replicated over T) ----
  conv5_lds<3, 16, 128, 128, 124, 124, 8, true, (long)32 * 3 * 128 * 128 - 4>
      <<<dim3(4 * 8, 1, 32), 256, 0, stream>>>(x, wc1, Y);
  {
    int HW = 124 * 124, M = 32 * HW;
    bn_partial<<<16 * S, 256, 0, stream>>>(Y, 16, M, HW, 1.0 / HW, psum, psq, S);
    bn_finalize<<<1, 64, 0, stream>>>(psum, psq, g1, b1, scale, shift, 16, S,
                                      1.0 / (double)M);
  }
  {  // pool1 out: (5,32,16,62,PWp=64)
    int total = BATCH * 16 * 62 * 64;
    plif_pool<<<(total + 255) / 256, 256, 0, stream>>>(
        Y, scale, shift, wl1, P, 16, 124, 124, 62, 62, 64, 0L);
  }

  // ---- block 2: conv2 (160,16,62x64p) -> (160,32,58,58) ----
  conv5_lds<16, 16, 62, 64, 58, 58, 4, false, 0>
      <<<dim3(2 * 4, 2, 160), 256, 0, stream>>>(P, wc2, Y);
  {
    int HW = 58 * 58, M = 160 * HW;
    bn_partial<<<32 * S, 256, 0, stream>>>(Y, 32, M, HW, 1.0 / HW, psum, psq, S);
    bn_finalize<<<1, 64, 0, stream>>>(psum, psq, g2, b2, scale, shift, 32, S,
                                      1.0 / (double)M);
  }
  {  // pool2 out: (5,32,32,29,PWp=32)
    int total = BATCH * 32 * 29 * 32;
    plif_pool<<<(total + 255) / 256, 256, 0, stream>>>(
        Y, scale, shift, wl2, P, 32, 58, 58, 29, 29, 32,
        (long)BATCH * 32 * 58 * 58);
  }

  // ---- block 3: conv3 (160,32,29x32p) -> (160,32,25,25) ----
  conv5_lds<32, 16, 29, 32, 25, 25, 2, false, 0>
      <<<dim3(1 * 2, 2, 160), 256, 0, stream>>>(P, wc3, Y);
  {
    int HW = 25 * 25, M = 160 * HW;
    bn_partial<<<32 * S, 256, 0, stream>>>(Y, 32, M, HW, 1.0 / HW, psum, psq, S);
    bn_finalize<<<1, 64, 0, stream>>>(psum, psq, g3, b3, scale, shift, 32, S,
                                      1.0 / (double)M);
  }
  {  // pool3 out: (5,32,32,12,12)
    int total = BATCH * 32 * 12 * 12;
    plif_pool<<<(total + 255) / 256, 256, 0, stream>>>(
        Y, scale, shift, wl3, P, 32, 25, 25, 12, 12, 12,
        (long)BATCH * 32 * 25 * 25);
  }

  // ---- block 4: conv4 (160,32,12,12) -> (160,64,8,8) ----
  conv4_rb<<<dim3(4, 160), 256, 0, stream>>>(P, wc4, Y);
  {
    int HW = 8 * 8, M = 160 * HW;
    bn_partial<<<64 * S, 256, 0, stream>>>(Y, 64, M, HW, 1.0 / HW, psum, psq, S);
    bn_finalize<<<1, 64, 0, stream>>>(psum, psq, g4, b4, scale, shift, 64, S,
                                      1.0 / (double)M);
  }
  {  // pool4 out: (5,32,64,4,4)
    int total = BATCH * 64 * 4 * 4;
    plif_pool<<<(total + 255) / 256, 256, 0, stream>>>(
        Y, scale, shift, wl4, P, 64, 8, 8, 4, 4, 4, (long)BATCH * 64 * 8 * 8);
  }

  // ---- FC head ----
  float* h1 = Y;
  float* s1 = P;
  float* h2 = Y + 163840;
  fc1_tiled<<<dim3(4, 20), 256, 0, stream>>>(P, fc1w, h1);
  plif_fc<<<(BATCH * 1024 + 255) / 256, 256, 0, stream>>>(h1, fc1b, wl5, s1,
                                                          1024);
  fc_kernel<<<160 * 1, 256, 0, stream>>>(s1, fc2w, h2, 1024, 10, 1);
  plif_mean<<<(BATCH * 10 + 255) / 256, 256, 0, stream>>>(h2, fc2b, wl6, out,
                                                          10);
}